// Round 7
// baseline (484.621 us; speedup 1.0000x reference)
//
#include <hip/hip_runtime.h>
#include <hip/hip_bf16.h>

// KroneckerMixer: B=64, N=1024, K=64, BASIS=8, T=0.2, 20 sinkhorn iters.
// R7 pipeline (bf16 path, ws >= 36.5 MB):
//   k_front : fused.
//     Blocks 0..15 = A-sinkhorn u/v solver, E0 REGISTER-RESIDENT (64 VGPR:
//       e4[4][4] float4; wave w owns rows 4w..4w+3, lane owns 16 cols).
//       Row pass: reg dot + DPP reduce + shfl(63) -> u in registers.
//       Col pass: reg FMA -> cross-wave LDS reduce cps[16][1024].
//       Cross-block: 1 sc1 store + 16 sc1 loads / thread / iter (ping-pong P),
//       one flat 16-way relaxed barrier per iter. No E0 L2 streaming at all.
//       Iter0 emits Eh/El bf16 hi/lo (E0 fp32 only in fallback mode).
//     Blocks 16..271 = W-path (R5/R6-verified): per-n 64x64 sinkhorn +
//       x_local matmul -> XL fp32 [n][c].
//   k_xt    : transpose + v-scale + hi/lo split XL -> XTh/XTl bf16 [c][n].
//   k_gemm3 : out[m][c] = u_m*(Eh*XTh + El*XTh + Eh*XTl), 16x16x32 bf16 MFMA,
//             DOUBLE-BUFFERED LDS + global prefetch (1 barrier / K-tile) —
//             needed because grid = 1 block/CU (no TLP to hide vmcnt drain).
// Fallback (small ws): fp32 k_gemm with u/v folded.

#define N_DIM 1024
#define INV_T 5.0f
#define NBAR 16  // A-sinkhorn barrier blocks

typedef __attribute__((ext_vector_type(8))) short short8;
typedef __attribute__((ext_vector_type(4))) float float4v;

// ---------------- wave64 sum reduction via DPP (VALU pipe) -------------------
// Result valid in lane 63.
__device__ __forceinline__ float wave_red_sum(float x) {
#define DPP_ADD(C)                                                            \
  {                                                                           \
    int _y = __builtin_amdgcn_update_dpp(0, __float_as_int(x), (C), 0xf, 0xf, \
                                         true);                               \
    x += __int_as_float(_y);                                                  \
  }
  DPP_ADD(0x111);
  DPP_ADD(0x112);
  DPP_ADD(0x114);
  DPP_ADD(0x118);
  DPP_ADD(0x142);
  DPP_ADD(0x143);
#undef DPP_ADD
  return x;
}

// ---- flat 16-way grid barrier, monotonic, fully relaxed (sc1 counters) ------
// All cross-block payload moves via sc1 (agent-scope relaxed) accesses, so no
// acquire/release cache maintenance is needed anywhere. ctrl: gen@word0,
// cnt@word32 (separate lines, 4096 B zeroed by launcher). bi = 0..19.
__device__ __forceinline__ void gbar3(unsigned* ctrl, int bi) {
  __syncthreads();
  if (threadIdx.x == 0) {
    unsigned* gen = ctrl;
    unsigned* cnt = ctrl + 32;
    unsigned a = __hip_atomic_fetch_add(cnt, 1u, __ATOMIC_RELAXED,
                                        __HIP_MEMORY_SCOPE_AGENT);
    if (a == (unsigned)bi * (unsigned)NBAR + (unsigned)(NBAR - 1)) {
      __hip_atomic_fetch_add(gen, 1u, __ATOMIC_RELAXED,
                             __HIP_MEMORY_SCOPE_AGENT);
    } else {
      while (__hip_atomic_load(gen, __ATOMIC_RELAXED,
                               __HIP_MEMORY_SCOPE_AGENT) <= (unsigned)bi)
        __builtin_amdgcn_s_sleep(2);
    }
  }
  __syncthreads();
}

// ---------------- kernel 1: fused sinkA(u,v) + wpath -------------------------
// grid 272 x 1024. smem: sinkA {v_s[1024], cps[16][1024]} = 17408 floats;
// wpath {uS2[64], ps[16*64], Ws[4096], Xs[64*65]} = 9344 floats (union).
__global__ __launch_bounds__(1024, 4) void k_front(
    const float* __restrict__ x, const float* __restrict__ L,
    const float* __restrict__ W1, const float* __restrict__ WV,
    float* __restrict__ E0, __hip_bfloat16* __restrict__ Eh,
    __hip_bfloat16* __restrict__ El, float* __restrict__ P,
    unsigned* __restrict__ ctrl, float* __restrict__ u_g,
    float* __restrict__ v_g, float* __restrict__ XL, int write_bf16) {
  __shared__ __align__(16) float smem[17408];
  const int t = threadIdx.x;
  const int bid = blockIdx.x;
  const int lane = t & 63;
  const int w = t >> 6;  // 0..15

  if (bid < NBAR) {
    // =================== A-sinkhorn u/v role (E0 in registers) ==============
    float* v_s = smem;         // [1024]
    float* cps = smem + 1024;  // [16][1024]
    const int r0 = bid * 64;

    float4 e4[4][4];  // e4[row j][quad q] : rows r0+4w+j, cols lane*16+4q..
    float p[4];
    // ---- iter-0 row pass fused with E materialization
#pragma unroll
    for (int j = 0; j < 4; ++j) {
      const int r = r0 + 4 * w + j;
      const float4* Lr = (const float4*)(L + (size_t)r * N_DIM + lane * 16);
      float pj = 0.f;
#pragma unroll
      for (int q = 0; q < 4; ++q) {
        float4 f = Lr[q];
        float4 g;
        g.x = __expf(f.x * INV_T);
        g.y = __expf(f.y * INV_T);
        g.z = __expf(f.z * INV_T);
        g.w = __expf(f.w * INV_T);
        e4[j][q] = g;
        pj += (g.x + g.y) + (g.z + g.w);
      }
      p[j] = pj;
      const size_t off = (size_t)r * N_DIM + lane * 16;
      if (write_bf16) {
        __align__(16) ushort hb[16], lb[16];
#pragma unroll
        for (int q = 0; q < 4; ++q) {
          const float ev[4] = {e4[j][q].x, e4[j][q].y, e4[j][q].z, e4[j][q].w};
#pragma unroll
          for (int z = 0; z < 4; ++z) {
            __hip_bfloat16 h = __float2bfloat16(ev[z]);
            hb[4 * q + z] = *(ushort*)&h;
            __hip_bfloat16 l = __float2bfloat16(ev[z] - __bfloat162float(h));
            lb[4 * q + z] = *(ushort*)&l;
          }
        }
        *(uint4*)&Eh[off] = *(uint4*)&hb[0];
        *(uint4*)&Eh[off + 8] = *(uint4*)&hb[8];
        *(uint4*)&El[off] = *(uint4*)&lb[0];
        *(uint4*)&El[off + 8] = *(uint4*)&lb[8];
      } else {
        float4* Er = (float4*)(E0 + off);
#pragma unroll
        for (int q = 0; q < 4; ++q) Er[q] = e4[j][q];
      }
    }

    float u_j[4];
    for (int it = 0; it < 20; ++it) {
      // ---- row pass (it>0): p_j = sum_c e[j][c] * v[c], v from LDS
      if (it > 0) {
#pragma unroll
        for (int j = 0; j < 4; ++j) {
          float pj = 0.f;
#pragma unroll
          for (int q = 0; q < 4; ++q) {
            float4 vv = *(const float4*)&v_s[lane * 16 + 4 * q];
            float4 e = e4[j][q];
            pj += e.x * vv.x + e.y * vv.y + e.z * vv.z + e.w * vv.w;
          }
          p[j] = pj;
        }
      }
#pragma unroll
      for (int j = 0; j < 4; ++j) {
        float pr = wave_red_sum(p[j]);
        u_j[j] = 1.0f / __shfl(pr, 63);  // wave-uniform u, stays in regs
      }
      // ---- col partials for this thread's 16 columns (pure register FMA)
#pragma unroll
      for (int q = 0; q < 4; ++q) {
        float4 cp = {0.f, 0.f, 0.f, 0.f};
#pragma unroll
        for (int j = 0; j < 4; ++j) {
          float4 e = e4[j][q];
          cp.x += e.x * u_j[j];
          cp.y += e.y * u_j[j];
          cp.z += e.z * u_j[j];
          cp.w += e.w * u_j[j];
        }
        *(float4*)&cps[w * N_DIM + lane * 16 + 4 * q] = cp;
      }
      __syncthreads();
      // ---- cross-wave reduce: thread t owns col t (stride-4KB b32, 2/bank)
      float s = 0.f;
#pragma unroll
      for (int ww = 0; ww < 16; ++ww) s += cps[ww * N_DIM + t];
      float* Pw = P + (it & 1) * (NBAR * N_DIM);
      __hip_atomic_store(&Pw[bid * N_DIM + t], s, __ATOMIC_RELAXED,
                         __HIP_MEMORY_SCOPE_AGENT);
      gbar3(ctrl, it);
      // ---- v update: 16 sc1 loads per thread
      float s2 = 0.f;
#pragma unroll
      for (int pb = 0; pb < NBAR; ++pb)
        s2 += __hip_atomic_load(&Pw[pb * N_DIM + t], __ATOMIC_RELAXED,
                                __HIP_MEMORY_SCOPE_AGENT);
      v_s[t] = 1.0f / s2;
      __syncthreads();
    }
    // ---- epilogue: u (lane 0 per wave), v (block 0)
    if (lane == 0) {
#pragma unroll
      for (int j = 0; j < 4; ++j) u_g[r0 + 4 * w + j] = u_j[j];
    }
    if (bid == 0) v_g[t] = v_s[t];
  } else {
    // =================== W-path role: 4 n's sequentially ===================
    float* uS2 = smem;                    // [64]
    float* ps = smem + 64;                // [16][64]
    float* Ws = smem + 64 + 1024;         // [64*64]
    float* Xs = smem + 64 + 1024 + 4096;  // [64*65]
    const int base_n = (bid - NBAR) * 4;

    for (int s = 0; s < 4; ++s) {
      const int n = base_n + s;
      float w1[8];
#pragma unroll
      for (int k = 0; k < 8; ++k) w1[k] = W1[n * 8 + k];

      // element j: (row i = j*16 + w, col o = lane)
      float ew[4];
#pragma unroll
      for (int j = 0; j < 4; ++j) {
        const int f = j * 1024 + t;
        float acc = 0.f;
#pragma unroll
        for (int k = 0; k < 8; ++k) acc += w1[k] * WV[k * 4096 + f];
        ew[j] = __expf(acc * INV_T);
      }

      float vt = 1.0f;
      for (int it = 0; it < 20; ++it) {
#pragma unroll
        for (int j = 0; j < 4; ++j) {
          float pp = wave_red_sum(ew[j] * vt);
          if (lane == 63) uS2[j * 16 + w] = 1.0f / pp;
        }
        // uS2[j*16+w] written & read by the same wave: in-order LDS pipe
        float cp = 0.f;
#pragma unroll
        for (int j = 0; j < 4; ++j) cp += ew[j] * uS2[j * 16 + w];
        ps[w * 64 + lane] = cp;
        __syncthreads();
        float sv = 0.f;
#pragma unroll
        for (int ww = 0; ww < 16; ++ww) sv += ps[ww * 64 + lane];
        vt = 1.0f / sv;
        __syncthreads();
      }

#pragma unroll
      for (int j = 0; j < 4; ++j)
        Ws[(j * 16 + w) * 64 + lane] = ew[j] * uS2[j * 16 + w] * vt;
#pragma unroll
      for (int j = 0; j < 4; ++j) {
        const int idx = j * 1024 + t;  // batch bb = idx>>6, col i = idx&63
        Xs[(idx >> 6) * 65 + (idx & 63)] =
            x[(size_t)(idx >> 6) * 65536 + n * 64 + (idx & 63)];
      }
      __syncthreads();

      // x_local[bb][o] = sum_i Xs[bb][i] * Ws[i][o]; thread = (bb, 4 o's)
      const int bb = t >> 4;
      const int o4 = (t & 15) * 4;
      float4 a4 = {0.f, 0.f, 0.f, 0.f};
#pragma unroll 4
      for (int i = 0; i < 64; ++i) {
        float4 w4 = *(const float4*)&Ws[i * 64 + o4];
        float xv = Xs[bb * 65 + i];
        a4.x += xv * w4.x;
        a4.y += xv * w4.y;
        a4.z += xv * w4.z;
        a4.w += xv * w4.w;
      }
      *(float4*)&XL[(size_t)n * 4096 + bb * 64 + o4] = a4;
      __syncthreads();  // before next n reuses LDS
    }
  }
}

// ---------------- kernel 2b: transpose + v-scale + hi/lo split ---------------
// XTh/XTl[c][n] = hi/lo bf16 of (v[n] * XL[n][c]).
__global__ __launch_bounds__(256) void k_xt(const float* __restrict__ XL,
                                            const float* __restrict__ v_g,
                                            __hip_bfloat16* __restrict__ XTh,
                                            __hip_bfloat16* __restrict__ XTl) {
  __shared__ float T[64 * 68];
  __shared__ float vsh[64];
  const int t = threadIdx.x;
  const int n0 = blockIdx.x * 64;
  const int c0 = blockIdx.y * 64;
  if (t < 64) vsh[t] = v_g[n0 + t];
  {
    const int r = t >> 4;         // 0..15
    const int c4 = (t & 15) * 4;  // 0..60
#pragma unroll
    for (int p = 0; p < 4; ++p) {
      float4 f =
          *(const float4*)&XL[(size_t)(n0 + r + 16 * p) * 4096 + c0 + c4];
      *(float4*)&T[(r + 16 * p) * 68 + c4] = f;
    }
  }
  __syncthreads();
  const int cl = t >> 2;        // 0..63
  const int nb = (t & 3) * 16;  // 0,16,32,48
  __align__(16) __hip_bfloat16 hbuf[16];
  __align__(16) __hip_bfloat16 lbuf[16];
#pragma unroll
  for (int j = 0; j < 16; ++j) {
    float xv = T[(nb + j) * 68 + cl] * vsh[nb + j];
    __hip_bfloat16 h = __float2bfloat16(xv);
    hbuf[j] = h;
    lbuf[j] = __float2bfloat16(xv - __bfloat162float(h));
  }
  const size_t off = (size_t)(c0 + cl) * 1024 + n0 + nb;
  *(uint4*)&XTh[off] = *(uint4*)&hbuf[0];
  *(uint4*)&XTh[off + 8] = *(uint4*)&hbuf[8];
  *(uint4*)&XTl[off] = *(uint4*)&lbuf[0];
  *(uint4*)&XTl[off + 8] = *(uint4*)&lbuf[8];
}

// ---------------- kernel 3 (bf16): out = u ⊙ (Eh*XTh + El*XTh + Eh*XTl) ------
// D[m=1024][c=4096], 128x128 block tile, 4 waves each 64x64 of 16x16x32 MFMA.
// Double-buffered LDS + global prefetch: 1 barrier per K-tile.
#define LSTR 72  // padded LDS row stride (elements)
__global__ __launch_bounds__(256) void k_gemm3(
    const ushort* __restrict__ Eh, const ushort* __restrict__ El,
    const ushort* __restrict__ XTh, const ushort* __restrict__ XTl,
    const float* __restrict__ u_g, float* __restrict__ out) {
  __shared__ ushort As[2][128 * LSTR];
  __shared__ ushort Xs[2][128 * LSTR];
  __shared__ float ush[128];
  const int t = threadIdx.x;
  const int m0 = blockIdx.x * 128;
  const int c0 = blockIdx.y * 128;
  const int wid = t >> 6, lane = t & 63;
  const int wm = (wid & 1) * 64, wc = (wid >> 1) * 64;
  const int lm = lane & 15, q = lane >> 4;
  const int sr = t >> 1;        // staging row 0..127
  const int sc = (t & 1) * 32;  // staging k-offset: [sc, sc+32)
  if (t < 128) ush[t] = u_g[m0 + t];

  const ushort* Aseg[3] = {Eh, El, Eh};
  const ushort* Xseg[3] = {XTh, XTh, XTl};

  float4v acc[4][4];
#pragma unroll
  for (int i = 0; i < 4; ++i)
#pragma unroll
    for (int j = 0; j < 4; ++j) acc[i][j] = (float4v){0.f, 0.f, 0.f, 0.f};

  uint4 pa[4], px[4];  // prefetch registers
  auto FETCH = [&](int tt) {
    const int seg = tt >> 4;
    const int k0 = (tt & 15) * 64;
    const ushort* ag = Aseg[seg] + (size_t)(m0 + sr) * 1024 + k0 + sc;
    const ushort* xg = Xseg[seg] + (size_t)(c0 + sr) * 1024 + k0 + sc;
#pragma unroll
    for (int i = 0; i < 4; ++i) {
      pa[i] = *(const uint4*)(ag + 8 * i);
      px[i] = *(const uint4*)(xg + 8 * i);
    }
  };
  auto STAGE = [&](int buf) {
#pragma unroll
    for (int i = 0; i < 4; ++i) {
      *(uint4*)&As[buf][sr * LSTR + sc + 8 * i] = pa[i];
      *(uint4*)&Xs[buf][sr * LSTR + sc + 8 * i] = px[i];
    }
  };

  FETCH(0);
  STAGE(0);
  for (int tt = 0; tt < 48; ++tt) {
    __syncthreads();  // buf(tt) staged; everyone done reading buf(tt) prev use
    if (tt + 1 < 48) FETCH(tt + 1);  // global latency overlaps compute below
    const int buf = tt & 1;
#pragma unroll
    for (int kk = 0; kk < 2; ++kk) {
      short8 af[4], xf[4];
#pragma unroll
      for (int i = 0; i < 4; ++i)
        af[i] = *(const short8*)&As[buf][(wm + 16 * i + lm) * LSTR + kk * 32 +
                                         q * 8];
#pragma unroll
      for (int j = 0; j < 4; ++j)
        xf[j] = *(const short8*)&Xs[buf][(wc + 16 * j + lm) * LSTR + kk * 32 +
                                         q * 8];
#pragma unroll
      for (int i = 0; i < 4; ++i)
#pragma unroll
        for (int j = 0; j < 4; ++j)
          acc[i][j] = __builtin_amdgcn_mfma_f32_16x16x32_bf16(
              af[i], xf[j], acc[i][j], 0, 0, 0);
    }
    if (tt + 1 < 48) STAGE((tt + 1) & 1);  // other buffer: no read hazard
  }
  // epilogue: D row = q*4 + reg, col = lm (m89-verified); scale by u_m
#pragma unroll
  for (int i = 0; i < 4; ++i) {
#pragma unroll
    for (int j = 0; j < 4; ++j) {
      const int ml = wm + 16 * i + q * 4;
      const int m = m0 + ml;
      const int c = c0 + wc + 16 * j + lm;
      const int bb = c >> 6, o = c & 63;
      float* dst = out + (size_t)bb * 65536 + (size_t)m * 64 + o;
#pragma unroll
      for (int r = 0; r < 4; ++r) dst[64 * r] = acc[i][j][r] * ush[ml + r];
    }
  }
}

// ---------------- kernel 3 (fp32 fallback): out = u ⊙ (E0·(v⊙XL)) ------------
__global__ __launch_bounds__(256) void k_gemm(const float* __restrict__ E0,
                                              const float* __restrict__ XL,
                                              const float* __restrict__ u_g,
                                              const float* __restrict__ v_g,
                                              float* __restrict__ out) {
  __shared__ float Asm[32][132];
  __shared__ float Xsm[32][132];
  const int t = threadIdx.x;
  const int m0 = blockIdx.x * 128;
  const int c0 = blockIdx.y * 128;
  const int my8 = (t >> 4) * 8;
  const int cx8 = (t & 15) * 8;
  const int kk = t & 31;
  const int rr = t >> 5;
  float acc[8][8] = {};

  for (int k0 = 0; k0 < 1024; k0 += 32) {
#pragma unroll
    for (int s = 0; s < 16; ++s)
      Asm[kk][rr + 8 * s] = E0[(size_t)(m0 + rr + 8 * s) * 1024 + k0 + kk];
#pragma unroll
    for (int s = 0; s < 4; ++s) {
      const int krow = k0 + rr + 8 * s;
      float vk = v_g[krow];
      float4 f = *(const float4*)&XL[(size_t)krow * 4096 + c0 + kk * 4];
      f.x *= vk;
      f.y *= vk;
      f.z *= vk;
      f.w *= vk;
      *(float4*)&Xsm[rr + 8 * s][kk * 4] = f;
    }
    __syncthreads();
#pragma unroll
    for (int k = 0; k < 32; ++k) {
      float a[8], xv[8];
      *(float4*)&a[0] = *(const float4*)&Asm[k][my8];
      *(float4*)&a[4] = *(const float4*)&Asm[k][my8 + 4];
      *(float4*)&xv[0] = *(const float4*)&Xsm[k][cx8];
      *(float4*)&xv[4] = *(const float4*)&Xsm[k][cx8 + 4];
#pragma unroll
      for (int i = 0; i < 8; ++i)
#pragma unroll
        for (int j = 0; j < 8; ++j) acc[i][j] += a[i] * xv[j];
    }
    __syncthreads();
  }

#pragma unroll
  for (int i = 0; i < 8; ++i) {
    const int m = m0 + my8 + i;
    const float um = u_g[m];
    const int c = c0 + cx8;
    const int bb = c >> 6, o = c & 63;
    float* dst = out + (size_t)bb * 65536 + (size_t)m * 64 + o;
#pragma unroll
    for (int j = 0; j < 8; ++j) dst[j] = acc[i][j] * um;
  }
}

// ---------------- launcher ---------------------------------------------------
extern "C" void kernel_launch(void* const* d_in, const int* in_sizes, int n_in,
                              void* d_out, int out_size, void* d_ws,
                              size_t ws_size, hipStream_t stream) {
  (void)in_sizes;
  (void)n_in;
  (void)out_size;
  const float* x = (const float*)d_in[0];
  const float* Alog = (const float*)d_in[1];
  const float* W1 = (const float*)d_in[2];
  const float* WV = (const float*)d_in[3];
  float* out = (float*)d_out;

  char* ws = (char*)d_ws;
  const size_t MB = 1024 * 1024;
  const size_t KB = 1024;
  const bool use_bf16 = ws_size >= (36 * MB + 512 * KB);

  float* E0;
  float* XL;
  float* P;
  float* u_g;
  float* v_g;
  unsigned* ctrl;
  __hip_bfloat16 *Eh = nullptr, *El = nullptr, *XTh = nullptr, *XTl = nullptr;
  if (use_bf16) {
    Eh = (__hip_bfloat16*)(ws);             // 2 MB
    El = (__hip_bfloat16*)(ws + 2 * MB);    // 2 MB
    XTh = (__hip_bfloat16*)(ws + 4 * MB);   // 8 MB
    XTl = (__hip_bfloat16*)(ws + 12 * MB);  // 8 MB
    XL = (float*)(ws + 20 * MB);            // 16 MB -> ends 36 MB
    P = (float*)(ws + 36 * MB);             // 128 KB (2x ping-pong)
    u_g = (float*)(ws + 36 * MB + 128 * KB);
    v_g = (float*)(ws + 36 * MB + 132 * KB);
    ctrl = (unsigned*)(ws + 36 * MB + 136 * KB);  // 4 KB zeroed
    E0 = (float*)ws;                              // unused in bf16 mode
  } else {
    E0 = (float*)(ws);           // 4 MB
    XL = (float*)(ws + 4 * MB);  // 16 MB
    P = (float*)(ws + 20 * MB);  // 128 KB
    u_g = (float*)(ws + 20 * MB + 128 * KB);
    v_g = (float*)(ws + 20 * MB + 132 * KB);
    ctrl = (unsigned*)(ws + 20 * MB + 136 * KB);
  }

  hipMemsetAsync(ctrl, 0, 4096, stream);  // MUST cover all barrier counters
  hipLaunchKernelGGL(k_front, dim3(NBAR + 256), dim3(1024), 0, stream, x, Alog,
                     W1, WV, E0, Eh, El, P, ctrl, u_g, v_g, XL,
                     use_bf16 ? 1 : 0);
  if (use_bf16) {
    hipLaunchKernelGGL(k_xt, dim3(16, 64), dim3(256), 0, stream, XL, v_g, XTh,
                       XTl);
    hipLaunchKernelGGL(k_gemm3, dim3(8, 32), dim3(256), 0, stream,
                       (const ushort*)Eh, (const ushort*)El, (const ushort*)XTh,
                       (const ushort*)XTl, u_g, out);
  } else {
    hipLaunchKernelGGL(k_gemm, dim3(8, 32), dim3(256), 0, stream, E0, XL, u_g,
                       v_g, out);
  }
}

// Round 9
// 366.451 us; speedup vs baseline: 1.3225x; 1.3225x over previous
//
#include <hip/hip_runtime.h>
#include <hip/hip_bf16.h>

// KroneckerMixer: B=64, N=1024, K=64, BASIS=8, T=0.2, 20 sinkhorn iters.
// R9 = R8 with the compile error fixed (stray readlane experiment removed).
// Pipeline (bf16 path, ws >= 36.5 MB):
//   k_front : fused, grid 256x1024 (1 block/CU).
//     Blocks 0..15 = A-sinkhorn u/v solver, E0 register-resident (e4[4][4]
//       float4; wave w owns rows 4w..4w+3, lane owns 16 cols).
//       Row pass: reg dot + DPP reduce + shfl(63) broadcast.
//       Col pass: reg FMA -> cps2 COALESCED float4 LDS layout
//       [(w*4+q)*64+lane] (16B lane stride; R7's 64B stride was 4-8x bank
//       conflicted = +41us). Cross-block: 1 sc1 store + 16 sc1 loads /thread
//       /iter (ping-pong P), flat 16-way relaxed barrier. Iter0 emits Eh/El.
//     Blocks 16..255 = W-path: 4-5 n's each (240 blocks cover 1024 n's).
//   k_xt    : transpose + v-scale + hi/lo split XL -> XTh/XTl bf16 [c][n].
//   k_gemm3 : out[m][c] = u_m*(Eh*XTh + El*XTh + Eh*XTl), 16x16x32 bf16 MFMA.
//             Tile 128m x 64c -> grid (8,64) = 512 blocks = 2 blocks/CU so
//             cross-block TLP hides the staging barrier drain (R7's dbuf
//             regressed: register pressure).
// Fallback (small ws): fp32 k_gemm with u/v folded.

#define N_DIM 1024
#define INV_T 5.0f
#define NBAR 16  // A-sinkhorn barrier blocks

typedef __attribute__((ext_vector_type(8))) short short8;
typedef __attribute__((ext_vector_type(4))) float float4v;

// ---------------- wave64 sum reduction via DPP (VALU pipe) -------------------
// Result valid in lane 63.
__device__ __forceinline__ float wave_red_sum(float x) {
#define DPP_ADD(C)                                                            \
  {                                                                           \
    int _y = __builtin_amdgcn_update_dpp(0, __float_as_int(x), (C), 0xf, 0xf, \
                                         true);                               \
    x += __int_as_float(_y);                                                  \
  }
  DPP_ADD(0x111);
  DPP_ADD(0x112);
  DPP_ADD(0x114);
  DPP_ADD(0x118);
  DPP_ADD(0x142);
  DPP_ADD(0x143);
#undef DPP_ADD
  return x;
}

// ---- flat 16-way grid barrier, monotonic, fully relaxed (sc1 counters) ------
// ctrl: gen@word0, cnt@word32 (separate lines, 4096 B zeroed). bi = 0..19.
__device__ __forceinline__ void gbar3(unsigned* ctrl, int bi) {
  __syncthreads();
  if (threadIdx.x == 0) {
    unsigned* gen = ctrl;
    unsigned* cnt = ctrl + 32;
    unsigned a = __hip_atomic_fetch_add(cnt, 1u, __ATOMIC_RELAXED,
                                        __HIP_MEMORY_SCOPE_AGENT);
    if (a == (unsigned)bi * (unsigned)NBAR + (unsigned)(NBAR - 1)) {
      __hip_atomic_fetch_add(gen, 1u, __ATOMIC_RELAXED,
                             __HIP_MEMORY_SCOPE_AGENT);
    } else {
      while (__hip_atomic_load(gen, __ATOMIC_RELAXED,
                               __HIP_MEMORY_SCOPE_AGENT) <= (unsigned)bi)
        __builtin_amdgcn_s_sleep(2);
    }
  }
  __syncthreads();
}

// ---------------- kernel 1: fused sinkA(u,v) + wpath -------------------------
// grid 256 x 1024. smem union: sinkA {v_s[1024], cps2[4096] float4} = 17408 fl;
// wpath {uS2[64], ps[16*64], Ws[4096], Xs[64*65]} = 9344 fl.
__global__ __launch_bounds__(1024) void k_front(
    const float* __restrict__ x, const float* __restrict__ L,
    const float* __restrict__ W1, const float* __restrict__ WV,
    float* __restrict__ E0, __hip_bfloat16* __restrict__ Eh,
    __hip_bfloat16* __restrict__ El, float* __restrict__ P,
    unsigned* __restrict__ ctrl, float* __restrict__ u_g,
    float* __restrict__ v_g, float* __restrict__ XL, int write_bf16) {
  __shared__ __align__(16) float smem[17408];
  const int t = threadIdx.x;
  const int bid = blockIdx.x;
  const int lane = t & 63;
  const int w = t >> 6;  // 0..15

  if (bid < NBAR) {
    // =================== A-sinkhorn u/v role (E0 in registers) ==============
    float* v_s = smem;                      // [1024]
    float4* cps2 = (float4*)(smem + 1024);  // [4096] float4
    const int r0 = bid * 64;

    float4 e4[4][4];  // e4[row j][quad q]: rows r0+4w+j, cols lane*16+4q..
    float p[4];
    // ---- iter-0 row pass fused with E materialization
#pragma unroll
    for (int j = 0; j < 4; ++j) {
      const int r = r0 + 4 * w + j;
      const float4* Lr = (const float4*)(L + (size_t)r * N_DIM + lane * 16);
      float pj = 0.f;
#pragma unroll
      for (int q = 0; q < 4; ++q) {
        float4 f = Lr[q];
        float4 g;
        g.x = __expf(f.x * INV_T);
        g.y = __expf(f.y * INV_T);
        g.z = __expf(f.z * INV_T);
        g.w = __expf(f.w * INV_T);
        e4[j][q] = g;
        pj += (g.x + g.y) + (g.z + g.w);
      }
      p[j] = pj;
      const size_t off = (size_t)r * N_DIM + lane * 16;
      if (write_bf16) {
        __align__(16) ushort hb[16], lb[16];
#pragma unroll
        for (int q = 0; q < 4; ++q) {
          const float ev[4] = {e4[j][q].x, e4[j][q].y, e4[j][q].z, e4[j][q].w};
#pragma unroll
          for (int z = 0; z < 4; ++z) {
            __hip_bfloat16 h = __float2bfloat16(ev[z]);
            hb[4 * q + z] = *(ushort*)&h;
            __hip_bfloat16 l = __float2bfloat16(ev[z] - __bfloat162float(h));
            lb[4 * q + z] = *(ushort*)&l;
          }
        }
        *(uint4*)&Eh[off] = *(uint4*)&hb[0];
        *(uint4*)&Eh[off + 8] = *(uint4*)&hb[8];
        *(uint4*)&El[off] = *(uint4*)&lb[0];
        *(uint4*)&El[off + 8] = *(uint4*)&lb[8];
      } else {
        float4* Er = (float4*)(E0 + off);
#pragma unroll
        for (int q = 0; q < 4; ++q) Er[q] = e4[j][q];
      }
    }

    float u_j[4];
    for (int it = 0; it < 20; ++it) {
      // ---- row pass (it>0): p_j = sum_c e[j][c]*v[c], v broadcast from LDS
      if (it > 0) {
#pragma unroll
        for (int j = 0; j < 4; ++j) {
          float pj = 0.f;
#pragma unroll
          for (int q = 0; q < 4; ++q) {
            float4 vv = *(const float4*)&v_s[lane * 16 + 4 * q];
            float4 e = e4[j][q];
            pj += e.x * vv.x + e.y * vv.y + e.z * vv.z + e.w * vv.w;
          }
          p[j] = pj;
        }
      }
#pragma unroll
      for (int j = 0; j < 4; ++j) {
        float pr = wave_red_sum(p[j]);
        u_j[j] = 1.0f / __shfl(pr, 63);  // wave-uniform broadcast
      }
      // ---- col partials: COALESCED cps2[(w*4+q)*64 + lane] (16B lane stride)
#pragma unroll
      for (int q = 0; q < 4; ++q) {
        float4 cp;
        cp.x = e4[0][q].x * u_j[0] + e4[1][q].x * u_j[1] +
               e4[2][q].x * u_j[2] + e4[3][q].x * u_j[3];
        cp.y = e4[0][q].y * u_j[0] + e4[1][q].y * u_j[1] +
               e4[2][q].y * u_j[2] + e4[3][q].y * u_j[3];
        cp.z = e4[0][q].z * u_j[0] + e4[1][q].z * u_j[1] +
               e4[2][q].z * u_j[2] + e4[3][q].z * u_j[3];
        cp.w = e4[0][q].w * u_j[0] + e4[1][q].w * u_j[1] +
               e4[2][q].w * u_j[2] + e4[3][q].w * u_j[3];
        cps2[(w * 4 + q) * 64 + lane] = cp;
      }
      __syncthreads();
      // ---- cross-wave reduce: thread t owns col t
      //      col t = (t>>4)*16 + ((t>>2)&3)*4 + (t&3)
      {
        const int lr = t >> 4, qr = (t >> 2) & 3, zr = t & 3;
        float s = 0.f;
#pragma unroll
        for (int ww = 0; ww < 16; ++ww)
          s += ((const float*)&cps2[(ww * 4 + qr) * 64 + lr])[zr];
        float* Pw = P + (it & 1) * (NBAR * N_DIM);
        __hip_atomic_store(&Pw[bid * N_DIM + t], s, __ATOMIC_RELAXED,
                           __HIP_MEMORY_SCOPE_AGENT);
        gbar3(ctrl, it);
        // ---- v update: 16 sc1 loads per thread
        float s2 = 0.f;
#pragma unroll
        for (int pb = 0; pb < NBAR; ++pb)
          s2 += __hip_atomic_load(&Pw[pb * N_DIM + t], __ATOMIC_RELAXED,
                                  __HIP_MEMORY_SCOPE_AGENT);
        v_s[t] = 1.0f / s2;
      }
      __syncthreads();
    }
    // ---- epilogue: u (lane 0 per wave), v (block 0)
    if (lane == 0) {
#pragma unroll
      for (int j = 0; j < 4; ++j) u_g[r0 + 4 * w + j] = u_j[j];
    }
    if (bid == 0) v_g[t] = v_s[t];
  } else {
    // =================== W-path role: 4-5 n's sequentially ==================
    float* uS2 = smem;                    // [64]
    float* ps = smem + 64;                // [16][64]
    float* Ws = smem + 64 + 1024;         // [64*64]
    float* Xs = smem + 64 + 1024 + 4096;  // [64*65]
    const int widx = bid - NBAR;          // 0..239
    int n_begin, n_cnt;
    if (widx < 64) {
      n_begin = widx * 5;
      n_cnt = 5;
    } else {
      n_begin = 320 + (widx - 64) * 4;
      n_cnt = 4;
    }

    for (int s = 0; s < n_cnt; ++s) {
      const int n = n_begin + s;
      float w1[8];
#pragma unroll
      for (int k = 0; k < 8; ++k) w1[k] = W1[n * 8 + k];

      // element j: (row i = j*16 + w, col o = lane)
      float ew[4];
#pragma unroll
      for (int j = 0; j < 4; ++j) {
        const int f = j * 1024 + t;
        float acc = 0.f;
#pragma unroll
        for (int k = 0; k < 8; ++k) acc += w1[k] * WV[k * 4096 + f];
        ew[j] = __expf(acc * INV_T);
      }

      float vt = 1.0f;
      for (int it = 0; it < 20; ++it) {
#pragma unroll
        for (int j = 0; j < 4; ++j) {
          float pp = wave_red_sum(ew[j] * vt);
          if (lane == 63) uS2[j * 16 + w] = 1.0f / pp;
        }
        // uS2[j*16+w] written & read by the same wave: in-order LDS pipe
        float cp = 0.f;
#pragma unroll
        for (int j = 0; j < 4; ++j) cp += ew[j] * uS2[j * 16 + w];
        ps[w * 64 + lane] = cp;
        __syncthreads();
        float sv = 0.f;
#pragma unroll
        for (int ww = 0; ww < 16; ++ww) sv += ps[ww * 64 + lane];
        vt = 1.0f / sv;
        __syncthreads();
      }

#pragma unroll
      for (int j = 0; j < 4; ++j)
        Ws[(j * 16 + w) * 64 + lane] = ew[j] * uS2[j * 16 + w] * vt;
#pragma unroll
      for (int j = 0; j < 4; ++j) {
        const int idx = j * 1024 + t;  // batch bb = idx>>6, col i = idx&63
        Xs[(idx >> 6) * 65 + (idx & 63)] =
            x[(size_t)(idx >> 6) * 65536 + n * 64 + (idx & 63)];
      }
      __syncthreads();

      // x_local[bb][o] = sum_i Xs[bb][i] * Ws[i][o]; thread = (bb, 4 o's)
      const int bb = t >> 4;
      const int o4 = (t & 15) * 4;
      float4 a4 = {0.f, 0.f, 0.f, 0.f};
#pragma unroll 4
      for (int i = 0; i < 64; ++i) {
        float4 w4 = *(const float4*)&Ws[i * 64 + o4];
        float xv = Xs[bb * 65 + i];
        a4.x += xv * w4.x;
        a4.y += xv * w4.y;
        a4.z += xv * w4.z;
        a4.w += xv * w4.w;
      }
      *(float4*)&XL[(size_t)n * 4096 + bb * 64 + o4] = a4;
      __syncthreads();  // before next n reuses LDS
    }
  }
}

// ---------------- kernel 2b: transpose + v-scale + hi/lo split ---------------
// XTh/XTl[c][n] = hi/lo bf16 of (v[n] * XL[n][c]).
__global__ __launch_bounds__(256) void k_xt(const float* __restrict__ XL,
                                            const float* __restrict__ v_g,
                                            __hip_bfloat16* __restrict__ XTh,
                                            __hip_bfloat16* __restrict__ XTl) {
  __shared__ float T[64 * 68];
  __shared__ float vsh[64];
  const int t = threadIdx.x;
  const int n0 = blockIdx.x * 64;
  const int c0 = blockIdx.y * 64;
  if (t < 64) vsh[t] = v_g[n0 + t];
  {
    const int r = t >> 4;         // 0..15
    const int c4 = (t & 15) * 4;  // 0..60
#pragma unroll
    for (int p = 0; p < 4; ++p) {
      float4 f =
          *(const float4*)&XL[(size_t)(n0 + r + 16 * p) * 4096 + c0 + c4];
      *(float4*)&T[(r + 16 * p) * 68 + c4] = f;
    }
  }
  __syncthreads();
  const int cl = t >> 2;        // 0..63
  const int nb = (t & 3) * 16;  // 0,16,32,48
  __align__(16) __hip_bfloat16 hbuf[16];
  __align__(16) __hip_bfloat16 lbuf[16];
#pragma unroll
  for (int j = 0; j < 16; ++j) {
    float xv = T[(nb + j) * 68 + cl] * vsh[nb + j];
    __hip_bfloat16 h = __float2bfloat16(xv);
    hbuf[j] = h;
    lbuf[j] = __float2bfloat16(xv - __bfloat162float(h));
  }
  const size_t off = (size_t)(c0 + cl) * 1024 + n0 + nb;
  *(uint4*)&XTh[off] = *(uint4*)&hbuf[0];
  *(uint4*)&XTh[off + 8] = *(uint4*)&hbuf[8];
  *(uint4*)&XTl[off] = *(uint4*)&lbuf[0];
  *(uint4*)&XTl[off + 8] = *(uint4*)&lbuf[8];
}

// ---------------- kernel 3 (bf16): out = u ⊙ (Eh*XTh + El*XTh + Eh*XTl) ------
// Tile 128m x 64c, grid (8,64) = 512 blocks = 2 blocks/CU (TLP hides barrier
// drain). 4 waves: wave (wid&1) -> m-half, (wid>>1) -> c-half of 64x32.
#define LSTR 72  // padded LDS row stride (elements)
__global__ __launch_bounds__(256) void k_gemm3(
    const ushort* __restrict__ Eh, const ushort* __restrict__ El,
    const ushort* __restrict__ XTh, const ushort* __restrict__ XTl,
    const float* __restrict__ u_g, float* __restrict__ out) {
  __shared__ ushort As[128 * LSTR];  // 18432 B
  __shared__ ushort Xs[64 * LSTR];   // 9216 B
  __shared__ float ush[128];
  const int t = threadIdx.x;
  const int m0 = blockIdx.x * 128;
  const int c0 = blockIdx.y * 64;
  const int wid = t >> 6, lane = t & 63;
  const int wm = (wid & 1) * 64, wc = (wid >> 1) * 32;
  const int lm = lane & 15, q = lane >> 4;
  const int sra = t >> 1;        // A staging row 0..127
  const int sca = (t & 1) * 32;  // A staging k-offset: [sca, sca+32)
  const int srx = t >> 2;        // X staging row 0..63
  const int scx = (t & 3) * 16;  // X staging k-offset: [scx, scx+16)
  if (t < 128) ush[t] = u_g[m0 + t];

  float4v acc[4][2];
#pragma unroll
  for (int i = 0; i < 4; ++i)
#pragma unroll
    for (int j = 0; j < 2; ++j) acc[i][j] = (float4v){0.f, 0.f, 0.f, 0.f};

  for (int seg = 0; seg < 3; ++seg) {
    const ushort* Ag = (seg == 1) ? El : Eh;
    const ushort* Xg = (seg == 2) ? XTl : XTh;
    for (int k0 = 0; k0 < 1024; k0 += 64) {
      __syncthreads();
      const ushort* ag = Ag + (size_t)(m0 + sra) * 1024 + k0 + sca;
      const ushort* xg = Xg + (size_t)(c0 + srx) * 1024 + k0 + scx;
      uint4 a0 = *(const uint4*)(ag);
      uint4 a1 = *(const uint4*)(ag + 8);
      uint4 a2 = *(const uint4*)(ag + 16);
      uint4 a3 = *(const uint4*)(ag + 24);
      uint4 x0 = *(const uint4*)(xg);
      uint4 x1 = *(const uint4*)(xg + 8);
      *(uint4*)&As[sra * LSTR + sca] = a0;
      *(uint4*)&As[sra * LSTR + sca + 8] = a1;
      *(uint4*)&As[sra * LSTR + sca + 16] = a2;
      *(uint4*)&As[sra * LSTR + sca + 24] = a3;
      *(uint4*)&Xs[srx * LSTR + scx] = x0;
      *(uint4*)&Xs[srx * LSTR + scx + 8] = x1;
      __syncthreads();
#pragma unroll
      for (int kk = 0; kk < 2; ++kk) {
        short8 af[4], xf[2];
#pragma unroll
        for (int i = 0; i < 4; ++i)
          af[i] = *(const short8*)&As[(wm + 16 * i + lm) * LSTR + kk * 32 +
                                      q * 8];
#pragma unroll
        for (int j = 0; j < 2; ++j)
          xf[j] = *(const short8*)&Xs[(wc + 16 * j + lm) * LSTR + kk * 32 +
                                      q * 8];
#pragma unroll
        for (int i = 0; i < 4; ++i)
#pragma unroll
          for (int j = 0; j < 2; ++j)
            acc[i][j] = __builtin_amdgcn_mfma_f32_16x16x32_bf16(
                af[i], xf[j], acc[i][j], 0, 0, 0);
      }
    }
  }
  // epilogue: D row = q*4 + reg, col = lm (m89-verified); scale by u_m
#pragma unroll
  for (int i = 0; i < 4; ++i) {
#pragma unroll
    for (int j = 0; j < 2; ++j) {
      const int ml = wm + 16 * i + q * 4;
      const int m = m0 + ml;
      const int c = c0 + wc + 16 * j + lm;
      const int bb = c >> 6, o = c & 63;
      float* dst = out + (size_t)bb * 65536 + (size_t)m * 64 + o;
#pragma unroll
      for (int r = 0; r < 4; ++r) dst[64 * r] = acc[i][j][r] * ush[ml + r];
    }
  }
}

// ---------------- kernel 3 (fp32 fallback): out = u ⊙ (E0·(v⊙XL)) ------------
__global__ __launch_bounds__(256) void k_gemm(const float* __restrict__ E0,
                                              const float* __restrict__ XL,
                                              const float* __restrict__ u_g,
                                              const float* __restrict__ v_g,
                                              float* __restrict__ out) {
  __shared__ float Asm[32][132];
  __shared__ float Xsm[32][132];
  const int t = threadIdx.x;
  const int m0 = blockIdx.x * 128;
  const int c0 = blockIdx.y * 128;
  const int my8 = (t >> 4) * 8;
  const int cx8 = (t & 15) * 8;
  const int kk = t & 31;
  const int rr = t >> 5;
  float acc[8][8] = {};

  for (int k0 = 0; k0 < 1024; k0 += 32) {
#pragma unroll
    for (int s = 0; s < 16; ++s)
      Asm[kk][rr + 8 * s] = E0[(size_t)(m0 + rr + 8 * s) * 1024 + k0 + kk];
#pragma unroll
    for (int s = 0; s < 4; ++s) {
      const int krow = k0 + rr + 8 * s;
      float vk = v_g[krow];
      float4 f = *(const float4*)&XL[(size_t)krow * 4096 + c0 + kk * 4];
      f.x *= vk;
      f.y *= vk;
      f.z *= vk;
      f.w *= vk;
      *(float4*)&Xsm[rr + 8 * s][kk * 4] = f;
    }
    __syncthreads();
#pragma unroll
    for (int k = 0; k < 32; ++k) {
      float a[8], xv[8];
      *(float4*)&a[0] = *(const float4*)&Asm[k][my8];
      *(float4*)&a[4] = *(const float4*)&Asm[k][my8 + 4];
      *(float4*)&xv[0] = *(const float4*)&Xsm[k][cx8];
      *(float4*)&xv[4] = *(const float4*)&Xsm[k][cx8 + 4];
#pragma unroll
      for (int i = 0; i < 8; ++i)
#pragma unroll
        for (int j = 0; j < 8; ++j) acc[i][j] += a[i] * xv[j];
    }
    __syncthreads();
  }

#pragma unroll
  for (int i = 0; i < 8; ++i) {
    const int m = m0 + my8 + i;
    const float um = u_g[m];
    const int c = c0 + cx8;
    const int bb = c >> 6, o = c & 63;
    float* dst = out + (size_t)bb * 65536 + (size_t)m * 64 + o;
#pragma unroll
    for (int j = 0; j < 8; ++j) dst[j] = acc[i][j] * um;
  }
}

// ---------------- launcher ---------------------------------------------------
extern "C" void kernel_launch(void* const* d_in, const int* in_sizes, int n_in,
                              void* d_out, int out_size, void* d_ws,
                              size_t ws_size, hipStream_t stream) {
  (void)in_sizes;
  (void)n_in;
  (void)out_size;
  const float* x = (const float*)d_in[0];
  const float* Alog = (const float*)d_in[1];
  const float* W1 = (const float*)d_in[2];
  const float* WV = (const float*)d_in[3];
  float* out = (float*)d_out;

  char* ws = (char*)d_ws;
  const size_t MB = 1024 * 1024;
  const size_t KB = 1024;
  const bool use_bf16 = ws_size >= (36 * MB + 512 * KB);

  float* E0;
  float* XL;
  float* P;
  float* u_g;
  float* v_g;
  unsigned* ctrl;
  __hip_bfloat16 *Eh = nullptr, *El = nullptr, *XTh = nullptr, *XTl = nullptr;
  if (use_bf16) {
    Eh = (__hip_bfloat16*)(ws);             // 2 MB
    El = (__hip_bfloat16*)(ws + 2 * MB);    // 2 MB
    XTh = (__hip_bfloat16*)(ws + 4 * MB);   // 8 MB
    XTl = (__hip_bfloat16*)(ws + 12 * MB);  // 8 MB
    XL = (float*)(ws + 20 * MB);            // 16 MB -> ends 36 MB
    P = (float*)(ws + 36 * MB);             // 128 KB (2x ping-pong)
    u_g = (float*)(ws + 36 * MB + 128 * KB);
    v_g = (float*)(ws + 36 * MB + 132 * KB);
    ctrl = (unsigned*)(ws + 36 * MB + 136 * KB);  // 4 KB zeroed
    E0 = (float*)ws;                              // unused in bf16 mode
  } else {
    E0 = (float*)(ws);           // 4 MB
    XL = (float*)(ws + 4 * MB);  // 16 MB
    P = (float*)(ws + 20 * MB);  // 128 KB
    u_g = (float*)(ws + 20 * MB + 128 * KB);
    v_g = (float*)(ws + 20 * MB + 132 * KB);
    ctrl = (unsigned*)(ws + 20 * MB + 136 * KB);
  }

  (void)hipMemsetAsync(ctrl, 0, 4096, stream);  // covers all barrier counters
  hipLaunchKernelGGL(k_front, dim3(256), dim3(1024), 0, stream, x, Alog, W1,
                     WV, E0, Eh, El, P, ctrl, u_g, v_g, XL, use_bf16 ? 1 : 0);
  if (use_bf16) {
    hipLaunchKernelGGL(k_xt, dim3(16, 64), dim3(256), 0, stream, XL, v_g, XTh,
                       XTl);
    hipLaunchKernelGGL(k_gemm3, dim3(8, 64), dim3(256), 0, stream,
                       (const ushort*)Eh, (const ushort*)El, (const ushort*)XTh,
                       (const ushort*)XTl, u_g, out);
  } else {
    hipLaunchKernelGGL(k_gemm, dim3(8, 32), dim3(256), 0, stream, E0, XL, u_g,
                       v_g, out);
  }
}